// Round 3
// baseline (427.637 us; speedup 1.0000x reference)
//
#include <hip/hip_runtime.h>

#define T_FRAMES 32768
#define ROWF 1629          // 543*3 floats per frame
#define NSEG 512
#define NVAL 122           // 42 hand + 80 lips values per frame
#define STRIDE 128         // stage row stride (floats)
#define PADI 16            // accumulator padding: one int/float per 64B line
#define K1_BLOCKS 2048

// -------------------------------------------------------------------------
// K1 (fused): one frame per wave (32768 waves). Computes keep flag, stages
// 122 resolved values per frame (kept frames only — K3 never reads dropped
// rows), accumulates lips finite-stats (LDS -> padded global atomics), then
// the LAST block to finish (device-scope counter + threadfence, the standard
// threadFenceReduction pattern) runs the keep->kept_t prefix scan inline.
// -------------------------------------------------------------------------
__global__ __launch_bounds__(1024) void k1_fused(
    const float* __restrict__ frames, const int* __restrict__ lips_idx,
    int* __restrict__ keep, float* __restrict__ lip_sum,
    int* __restrict__ lip_cnt, float* __restrict__ stage,
    int* __restrict__ counter, int* __restrict__ kept_t,
    int* __restrict__ Sp) {
  __shared__ float ls[80];
  __shared__ int lc[80];
  __shared__ int wsum[16];
  __shared__ int isLast;
  int tid = threadIdx.x;
  if (tid < 80) { ls[tid] = 0.0f; lc[tid] = 0; }
  __syncthreads();

  int lane = tid & 63;
  int wv = tid >> 6;                          // 0..15
  int t = blockIdx.x * 16 + wv;               // one frame per wave
  const float* f = frames + (size_t)t * ROWF;
  float* srow = stage + (size_t)t * STRIDE;

  // ---- hand: lane = j*2 + c for j in [0,21), c in {0,1} ----
  float hv = 0.0f;
  if (lane < 42) {
    int j = lane >> 1, c = lane & 1;
    float lh = f[(468 + j) * 3 + c];
    float rh = f[(522 + j) * 3 + c];
    float a = (c == 0) ? lh : (1.0f - lh);    // lh: [x, 1-y]
    float b = 1.0f - rh;                      // rh: [1-x, 1-y]
    a = (a == a) ? a : 0.0f;                  // nan_to_num
    b = (b == b) ? b : 0.0f;
    hv = a + b;
  }
  // wave-reduce (all summands >= 0, so !=0 test is order-independent)
  float s = hv;
  #pragma unroll
  for (int off = 32; off > 0; off >>= 1) s += __shfl_down(s, off);
  s = __shfl(s, 0);
  int kp = (s != 0.0f) ? 1 : 0;
  if (lane == 0) keep[t] = kp;

  if (kp) {                                   // wave-uniform branch
    if (lane < 42) srow[lane] = hv;
    // ---- lips: v = j*2 + c for j in [0,40), c in {0,1} ----
    #pragma unroll
    for (int p = 0; p < 2; ++p) {
      int v = lane + p * 64;
      if (v < 80) {
        int j = v >> 1, c = v & 1;
        float x = f[lips_idx[j] * 3 + c];
        srow[42 + v] = x;                     // NaN preserved for K3
        if (x == x) {
          atomicAdd(&ls[v], x);
          atomicAdd(&lc[v], 1);
        }
      }
    }
  }
  __syncthreads();
  if (tid < 80) {
    atomicAdd(&lip_sum[tid * PADI], ls[tid]);
    atomicAdd(&lip_cnt[tid * PADI], lc[tid]);
  }

  // ---- last-block-done: release writes, count completions ----
  __syncthreads();                            // drains vmcnt(0) on gfx950
  if (tid == 0) {
    __threadfence();                          // agent-scope release (wbl2)
    int prev = atomicAdd(counter, 1);         // device-scope by default
    isLast = (prev == K1_BLOCKS - 1) ? 1 : 0;
  }
  __syncthreads();
  if (!isLast) return;
  __threadfence();                            // agent-scope acquire (inv)

  // ---- inline prefix scan of keep[] -> kept_t[], S (1024 threads) ----
  const int PER = T_FRAMES / 1024;            // 32
  int base = tid * PER;
  int local = 0;
  #pragma unroll 8
  for (int k = 0; k < PER; ++k) local += keep[base + k];

  int scan = local;
  #pragma unroll
  for (int off = 1; off < 64; off <<= 1) {
    int n = __shfl_up(scan, off);
    if (lane >= off) scan += n;
  }
  if (lane == 63) wsum[wv] = scan;
  __syncthreads();
  if (tid < 16) {
    int v = wsum[tid];
    #pragma unroll
    for (int off = 1; off < 16; off <<= 1) {
      int n = __shfl_up(v, off);
      if (tid >= off) v += n;
    }
    wsum[tid] = v;
  }
  __syncthreads();
  int excl = ((wv == 0) ? 0 : wsum[wv - 1]) + (scan - local);
  for (int k = 0; k < PER; ++k) {             // re-read (keeps VGPRs low)
    if (keep[base + k]) kept_t[excl++] = base + k;
  }
  if (tid == 1023) Sp[0] = wsum[15];
}

// -------------------------------------------------------------------------
// K3: one block per segment; 512 threads = 4-way row split × 128 values.
// Segment i owns kept ranks [b[i], b[i+1)) with b[i] = (i*(S-1))>>9 (exact
// vs np.linspace->int32). Rank S-1 (seg 512) is dropped, matching JAX
// segment_sum OOB-drop. Stage rows read fully coalesced.
// -------------------------------------------------------------------------
__global__ __launch_bounds__(512) void k3_segments(
    const float* __restrict__ stage, const int* __restrict__ kept_t,
    const int* __restrict__ Sp, const float* __restrict__ lip_sum,
    const int* __restrict__ lip_cnt, float* __restrict__ out, int out_size) {
  __shared__ int seglist[128];
  __shared__ float part[4][128];
  int tid = threadIdx.x;
  int v = tid & 127;                          // value index 0..127 (122 used)
  int r = tid >> 7;                           // 0..3
  int seg = blockIdx.x;
  long long Sm1 = (long long)Sp[0] - 1;
  if (Sm1 < 0) Sm1 = 0;
  int lo = (int)(((long long)seg * Sm1) >> 9);
  int hi = (int)(((long long)(seg + 1) * Sm1) >> 9);
  int cnt = hi - lo;

  for (int k = tid; k < cnt; k += 512) seglist[k] = kept_t[lo + k];
  __syncthreads();

  float cm = 0.0f;                            // column mean (lips only)
  if (v >= 42 && v < NVAL) {
    int w = v - 42;
    int c = lip_cnt[w * PADI];
    cm = (c == 0) ? 0.0f : lip_sum[w * PADI] / (float)c;
  }

  float acc = 0.0f;
  if (v < NVAL) {
    for (int k = r; k < cnt; k += 4) {
      float x = stage[(size_t)seglist[k] * STRIDE + v];
      acc += (x == x) ? x : cm;               // hand values never NaN
    }
  }
  part[r][v] = acc;
  __syncthreads();
  if (r == 0 && v < NVAL) {
    float tot = part[0][v] + part[1][v] + part[2][v] + part[3][v];
    float mean = (cnt == 0) ? 0.0f : tot / (float)cnt;
    int o = seg * NVAL + v;
    if (o < out_size) out[o] = mean;
  }
}

// -------------------------------------------------------------------------
extern "C" void kernel_launch(void* const* d_in, const int* in_sizes, int n_in,
                              void* d_out, int out_size, void* d_ws, size_t ws_size,
                              hipStream_t stream) {
  const float* frames = (const float*)d_in[0];
  const int* lips_idx = (const int*)d_in[1];
  float* out = (float*)d_out;

  char* ws = (char*)d_ws;
  int* keep      = (int*)(ws);                     // 131072 B
  int* kept_t    = (int*)(ws + 131072);            // 131072 B
  int* Sp        = (int*)(ws + 262144);            // +0
  int* counter   = (int*)(ws + 262144 + 4);        // +4 (rest of 64B = pad)
  float* lip_sum = (float*)(ws + 262208);          // 80 * 64B = 5120 B
  int* lip_cnt   = (int*)(ws + 267328);            // 80 * 64B = 5120 B
  float* stage   = (float*)(ws + 274432);          // 32768*128*4 = 16 MiB

  // zero Sp/counter/lip accumulators (ws is poisoned before every call)
  hipMemsetAsync((void*)(ws + 262144), 0, 12288, stream);

  k1_fused<<<K1_BLOCKS, 1024, 0, stream>>>(frames, lips_idx, keep, lip_sum,
                                           lip_cnt, stage, counter, kept_t, Sp);
  k3_segments<<<NSEG, 512, 0, stream>>>(stage, kept_t, Sp, lip_sum, lip_cnt,
                                        out, out_size);
}

// Round 4
// 410.108 us; speedup vs baseline: 1.0427x; 1.0427x over previous
//
#include <hip/hip_runtime.h>

#define T_FRAMES 32768
#define ROWF 1629          // 543*3 floats per frame
#define NSEG 512
#define NVAL 122           // 42 hand + 80 lips values per frame
#define STRIDE 128         // stage row stride (floats)
#define G 8                // frames per K1 block
#define NBLK (T_FRAMES / G) // 4096 K1 blocks

// -------------------------------------------------------------------------
// K1: coalesced streaming. Each block bulk-copies G=8 contiguous frame rows
// (52128 B, 16B-aligned) global->LDS as float4, then wave w<8 gathers frame
// w's 122 values from LDS (scatter in LDS, not HBM), computes keep, stages
// the row, and accumulates lips finite-stats into per-block LDS. Block ends
// by writing DETERMINISTIC per-block partials (no global atomics).
// -------------------------------------------------------------------------
__global__ __launch_bounds__(1024) void k1_stream(
    const float* __restrict__ frames, const int* __restrict__ lips_idx,
    int* __restrict__ keep, float* __restrict__ psum, int* __restrict__ pcnt,
    float* __restrict__ stage) {
  __shared__ float buf[G * ROWF];             // 52128 B
  __shared__ float ls[80];
  __shared__ int lc[80];
  __shared__ int idx3[40];
  int tid = threadIdx.x;
  if (tid < 80) { ls[tid] = 0.0f; lc[tid] = 0; }
  if (tid < 40) idx3[tid] = lips_idx[tid] * 3;

  // ---- flat coalesced copy: 8 rows = 3258 float4 ----
  const float4* src = (const float4*)(frames + (size_t)blockIdx.x * (G * ROWF));
  float4* dst = (float4*)buf;
  #pragma unroll
  for (int i = tid; i < (G * ROWF) / 4; i += 1024) dst[i] = src[i];
  __syncthreads();

  int lane = tid & 63;
  int wv = tid >> 6;                          // 0..15; waves 0..7 gather
  if (wv < G) {
    const float* fb = buf + wv * ROWF;
    int t = blockIdx.x * G + wv;
    float* srow = stage + (size_t)t * STRIDE;

    // ---- hand: lane = j*2 + c, j in [0,21), c in {0,1} ----
    float hv = 0.0f;
    if (lane < 42) {
      int j = lane >> 1, c = lane & 1;
      float lh = fb[1404 + 3 * j + c];        // (468+j)*3+c
      float rh = fb[1566 + 3 * j + c];        // (522+j)*3+c
      float a = (c == 0) ? lh : (1.0f - lh);  // lh: [x, 1-y]
      float b = 1.0f - rh;                    // rh: [1-x, 1-y]
      a = (a == a) ? a : 0.0f;                // nan_to_num
      b = (b == b) ? b : 0.0f;
      hv = a + b;
      srow[lane] = hv;
    }
    // wave-reduce (summands >= 0, order-independent !=0 test)
    float s = hv;
    #pragma unroll
    for (int off = 32; off > 0; off >>= 1) s += __shfl_down(s, off);
    s = __shfl(s, 0);
    int kp = (s != 0.0f) ? 1 : 0;
    if (lane == 0) keep[t] = kp;

    // ---- lips: v = j*2 + c, j in [0,40), c in {0,1} ----
    #pragma unroll
    for (int p = 0; p < 2; ++p) {
      int v = lane + p * 64;
      if (v < 80) {
        int j = v >> 1, c = v & 1;
        float x = fb[idx3[j] + c];
        srow[42 + v] = x;                     // NaN preserved for K3
        if (kp && (x == x)) {
          atomicAdd(&ls[v], x);               // LDS atomics, cheap
          atomicAdd(&lc[v], 1);
        }
      }
    }
  }
  __syncthreads();
  if (tid < 80) {                             // layout [col][NBLK]: K2 reads coalesced
    psum[(size_t)tid * NBLK + blockIdx.x] = ls[tid];
    pcnt[(size_t)tid * NBLK + blockIdx.x] = lc[tid];
  }
}

// -------------------------------------------------------------------------
// K2: (a) reduce per-block lip partials -> lip_sum/lip_cnt (deterministic);
//     (b) prefix scan keep[] -> kept_t[], total S.
// -------------------------------------------------------------------------
__global__ __launch_bounds__(1024) void k2_scan(
    const int* __restrict__ keep, int* __restrict__ kept_t,
    int* __restrict__ Sp, const float* __restrict__ psum,
    const int* __restrict__ pcnt, float* __restrict__ lip_sum,
    int* __restrict__ lip_cnt) {
  __shared__ int wsum[16];
  int tid = threadIdx.x;
  int lane = tid & 63, wv = tid >> 6;

  // ---- (a) partial reduction: wave w handles cols w, w+16, ... ----
  for (int col = wv; col < 80; col += 16) {
    float s = 0.0f; int c = 0;
    for (int b = lane; b < NBLK; b += 64) {
      s += psum[(size_t)col * NBLK + b];
      c += pcnt[(size_t)col * NBLK + b];
    }
    #pragma unroll
    for (int off = 32; off > 0; off >>= 1) {
      s += __shfl_down(s, off);
      c += __shfl_down(c, off);
    }
    if (lane == 0) { lip_sum[col] = s; lip_cnt[col] = c; }
  }

  // ---- (b) scan ----
  const int PER = T_FRAMES / 1024;            // 32
  int base = tid * PER;
  int fl[PER];
  int local = 0;
  #pragma unroll
  for (int k = 0; k < PER; ++k) { fl[k] = keep[base + k]; local += fl[k]; }

  int scan = local;
  #pragma unroll
  for (int off = 1; off < 64; off <<= 1) {
    int n = __shfl_up(scan, off);
    if (lane >= off) scan += n;
  }
  if (lane == 63) wsum[wv] = scan;
  __syncthreads();
  if (tid < 16) {
    int v = wsum[tid];
    #pragma unroll
    for (int off = 1; off < 16; off <<= 1) {
      int n = __shfl_up(v, off);
      if (tid >= off) v += n;
    }
    wsum[tid] = v;
  }
  __syncthreads();
  int excl = ((wv == 0) ? 0 : wsum[wv - 1]) + (scan - local);
  #pragma unroll
  for (int k = 0; k < PER; ++k) {
    if (fl[k]) kept_t[excl++] = base + k;
  }
  if (tid == 1023) Sp[0] = wsum[15];
}

// -------------------------------------------------------------------------
// K3: one block per segment; 512 threads = 4-way row split × 128 values.
// b[i] = (i*(S-1))>>9 (exact vs np.linspace->int32); rank S-1 (seg 512)
// dropped, matching JAX segment_sum OOB-drop.
// -------------------------------------------------------------------------
__global__ __launch_bounds__(512) void k3_segments(
    const float* __restrict__ stage, const int* __restrict__ kept_t,
    const int* __restrict__ Sp, const float* __restrict__ lip_sum,
    const int* __restrict__ lip_cnt, float* __restrict__ out, int out_size) {
  __shared__ int seglist[128];
  __shared__ float part[4][128];
  int tid = threadIdx.x;
  int v = tid & 127;                          // value index (122 used)
  int r = tid >> 7;                           // 0..3
  int seg = blockIdx.x;
  long long Sm1 = (long long)Sp[0] - 1;
  if (Sm1 < 0) Sm1 = 0;
  int lo = (int)(((long long)seg * Sm1) >> 9);
  int hi = (int)(((long long)(seg + 1) * Sm1) >> 9);
  int cnt = hi - lo;

  for (int k = tid; k < cnt; k += 512) seglist[k] = kept_t[lo + k];
  __syncthreads();

  float cm = 0.0f;                            // column mean (lips only)
  if (v >= 42 && v < NVAL) {
    int w = v - 42;
    int c = lip_cnt[w];
    cm = (c == 0) ? 0.0f : lip_sum[w] / (float)c;
  }

  float acc = 0.0f;
  if (v < NVAL) {
    for (int k = r; k < cnt; k += 4) {
      float x = stage[(size_t)seglist[k] * STRIDE + v];
      acc += (x == x) ? x : cm;               // hand values never NaN
    }
  }
  part[r][v] = acc;
  __syncthreads();
  if (r == 0 && v < NVAL) {
    float tot = part[0][v] + part[1][v] + part[2][v] + part[3][v];
    float mean = (cnt == 0) ? 0.0f : tot / (float)cnt;
    int o = seg * NVAL + v;
    if (o < out_size) out[o] = mean;
  }
}

// -------------------------------------------------------------------------
extern "C" void kernel_launch(void* const* d_in, const int* in_sizes, int n_in,
                              void* d_out, int out_size, void* d_ws, size_t ws_size,
                              hipStream_t stream) {
  const float* frames = (const float*)d_in[0];
  const int* lips_idx = (const int*)d_in[1];
  float* out = (float*)d_out;

  char* ws = (char*)d_ws;
  int* keep      = (int*)(ws);                     // 131072 B
  int* kept_t    = (int*)(ws + 131072);            // 131072 B
  int* Sp        = (int*)(ws + 262144);            // 64 B
  float* lip_sum = (float*)(ws + 262208);          // 512 B
  int* lip_cnt   = (int*)(ws + 262720);            // 512 B
  float* psum    = (float*)(ws + 263232);          // 80*4096*4 = 1310720 B
  int* pcnt      = (int*)(ws + 1573952);           // 1310720 B
  float* stage   = (float*)(ws + 2884672);         // 32768*128*4 = 16 MiB

  // no zero-init needed: every word read is written first (no atomics)

  k1_stream<<<NBLK, 1024, 0, stream>>>(frames, lips_idx, keep, psum, pcnt,
                                       stage);
  k2_scan<<<1, 1024, 0, stream>>>(keep, kept_t, Sp, psum, pcnt, lip_sum,
                                  lip_cnt);
  k3_segments<<<NSEG, 512, 0, stream>>>(stage, kept_t, Sp, lip_sum, lip_cnt,
                                        out, out_size);
}

// Round 5
// 325.960 us; speedup vs baseline: 1.3119x; 1.2582x over previous
//
#include <hip/hip_runtime.h>

#define T_FRAMES 32768
#define ROWF 1629           // 543*3 floats per frame
#define NSEG 512
#define NVAL 122            // 42 hand + 80 lips values per frame
#define STRIDE 128          // stage row stride (floats)
#define K1_BLOCKS 512       // 512 blocks x 16 waves x 4 frames = 32768

// -------------------------------------------------------------------------
// K1: scattered gather (R2 shape — proven fastest), but 4 frames per wave
// for 4x memory-level parallelism: all 16 gather loads issued before any
// use. keep = ballot(hv!=0) (exact: summands >= 0). Lip finite-stats go
// LDS -> deterministic per-block partials (no global atomics, no memset).
// -------------------------------------------------------------------------
__global__ __launch_bounds__(1024) void k1_gather(
    const float* __restrict__ frames, const int* __restrict__ lips_idx,
    int* __restrict__ keep, float* __restrict__ psum, int* __restrict__ pcnt,
    float* __restrict__ stage) {
  __shared__ float ls[80];
  __shared__ int lc[80];
  __shared__ int idx3[40];
  int tid = threadIdx.x;
  if (tid < 80) { ls[tid] = 0.0f; lc[tid] = 0; }
  if (tid < 40) idx3[tid] = lips_idx[tid] * 3;
  __syncthreads();

  int lane = tid & 63;
  int wv = tid >> 6;                          // 0..15
  int t0 = (blockIdx.x * 16 + wv) * 4;        // 4 consecutive frames per wave

  // per-lane column offsets (same for all frames)
  int jh = lane >> 1, ch = lane & 1;
  int offL = 1404 + 3 * jh + ch;              // (468+j)*3+c
  int offR = 1566 + 3 * jh + ch;              // (522+j)*3+c
  int offA = idx3[lane >> 1] + (lane & 1);    // lip value v = lane  (0..63)
  int offB = (lane < 16) ? (idx3[(lane + 64) >> 1] + (lane & 1)) : 0; // v=64+lane

  // ---- issue all 16 independent gathers up front ----
  float lh[4], rh[4], xa[4], xb[4];
  #pragma unroll
  for (int ff = 0; ff < 4; ++ff) {
    const float* f = frames + (size_t)(t0 + ff) * ROWF;
    lh[ff] = (lane < 42) ? f[offL] : 0.0f;    // exec-masked loads
    rh[ff] = (lane < 42) ? f[offR] : 1.0f;
    xa[ff] = f[offA];
    xb[ff] = (lane < 16) ? f[offB] : 0.0f;
  }

  // ---- per-frame resolve ----
  #pragma unroll
  for (int ff = 0; ff < 4; ++ff) {
    int t = t0 + ff;
    float hv = 0.0f;
    if (lane < 42) {
      float a = ch ? (1.0f - lh[ff]) : lh[ff];   // lh: [x, 1-y]
      float b = 1.0f - rh[ff];                   // rh: [1-x, 1-y]
      a = (a == a) ? a : 0.0f;                   // nan_to_num
      b = (b == b) ? b : 0.0f;
      hv = a + b;
    }
    // keep iff hand sum != 0; summands >= 0 so sum!=0 <=> any element != 0
    int kp = (__ballot(hv != 0.0f) != 0ull) ? 1 : 0;
    if (lane == 0) keep[t] = kp;

    if (kp) {                                    // wave-uniform
      float* srow = stage + (size_t)t * STRIDE;
      if (lane < 42) srow[lane] = hv;
      float x = xa[ff];
      srow[42 + lane] = x;                       // NaN preserved for K3
      if (x == x) { atomicAdd(&ls[lane], x); atomicAdd(&lc[lane], 1); }
      if (lane < 16) {
        float y = xb[ff];
        srow[106 + lane] = y;
        if (y == y) { atomicAdd(&ls[64 + lane], y); atomicAdd(&lc[64 + lane], 1); }
      }
    }
  }

  __syncthreads();
  if (tid < 80) {                                // [block][80]: coalesced
    psum[blockIdx.x * 80 + tid] = ls[tid];
    pcnt[blockIdx.x * 80 + tid] = lc[tid];
  }
}

// -------------------------------------------------------------------------
// K2: (a) reduce 512 per-block lip partials (coalesced: lanes = adjacent
// cols); (b) prefix scan keep[] -> kept_t[], total S.
// -------------------------------------------------------------------------
__global__ __launch_bounds__(1024) void k2_scan(
    const int* __restrict__ keep, int* __restrict__ kept_t,
    int* __restrict__ Sp, const float* __restrict__ psum,
    const int* __restrict__ pcnt, float* __restrict__ lip_sum,
    int* __restrict__ lip_cnt) {
  __shared__ int wsum[16];
  int tid = threadIdx.x;
  int lane = tid & 63, wv = tid >> 6;

  // ---- (a) lip partial reduction ----
  if (tid < 80) {
    float s = 0.0f; int c = 0;
    for (int b = 0; b < K1_BLOCKS; ++b) {
      s += psum[b * 80 + tid];
      c += pcnt[b * 80 + tid];
    }
    lip_sum[tid] = s; lip_cnt[tid] = c;
  }

  // ---- (b) scan ----
  const int PER = T_FRAMES / 1024;            // 32
  int base = tid * PER;
  int fl[PER];
  int local = 0;
  #pragma unroll
  for (int k = 0; k < PER; ++k) { fl[k] = keep[base + k]; local += fl[k]; }

  int scan = local;
  #pragma unroll
  for (int off = 1; off < 64; off <<= 1) {
    int n = __shfl_up(scan, off);
    if (lane >= off) scan += n;
  }
  if (lane == 63) wsum[wv] = scan;
  __syncthreads();
  if (tid < 16) {
    int v = wsum[tid];
    #pragma unroll
    for (int off = 1; off < 16; off <<= 1) {
      int n = __shfl_up(v, off);
      if (tid >= off) v += n;
    }
    wsum[tid] = v;
  }
  __syncthreads();
  int excl = ((wv == 0) ? 0 : wsum[wv - 1]) + (scan - local);
  #pragma unroll
  for (int k = 0; k < PER; ++k) {
    if (fl[k]) kept_t[excl++] = base + k;
  }
  if (tid == 1023) Sp[0] = wsum[15];
}

// -------------------------------------------------------------------------
// K3: one block per segment; 512 threads = 4-way row split x 128 values.
// b[i] = (i*(S-1))>>9 (exact vs np.linspace->int32); rank S-1 (seg 512)
// dropped, matching JAX segment_sum OOB-drop. Stage rows read coalesced.
// -------------------------------------------------------------------------
__global__ __launch_bounds__(512) void k3_segments(
    const float* __restrict__ stage, const int* __restrict__ kept_t,
    const int* __restrict__ Sp, const float* __restrict__ lip_sum,
    const int* __restrict__ lip_cnt, float* __restrict__ out, int out_size) {
  __shared__ int seglist[128];
  __shared__ float part[4][128];
  int tid = threadIdx.x;
  int v = tid & 127;                          // value index (122 used)
  int r = tid >> 7;                           // 0..3
  int seg = blockIdx.x;
  long long Sm1 = (long long)Sp[0] - 1;
  if (Sm1 < 0) Sm1 = 0;
  int lo = (int)(((long long)seg * Sm1) >> 9);
  int hi = (int)(((long long)(seg + 1) * Sm1) >> 9);
  int cnt = hi - lo;

  for (int k = tid; k < cnt; k += 512) seglist[k] = kept_t[lo + k];
  __syncthreads();

  float cm = 0.0f;                            // column mean (lips only)
  if (v >= 42 && v < NVAL) {
    int w = v - 42;
    int c = lip_cnt[w];
    cm = (c == 0) ? 0.0f : lip_sum[w] / (float)c;
  }

  float acc = 0.0f;
  if (v < NVAL) {
    for (int k = r; k < cnt; k += 4) {
      float x = stage[(size_t)seglist[k] * STRIDE + v];
      acc += (x == x) ? x : cm;               // hand values never NaN
    }
  }
  part[r][v] = acc;
  __syncthreads();
  if (r == 0 && v < NVAL) {
    float tot = part[0][v] + part[1][v] + part[2][v] + part[3][v];
    float mean = (cnt == 0) ? 0.0f : tot / (float)cnt;
    int o = seg * NVAL + v;
    if (o < out_size) out[o] = mean;
  }
}

// -------------------------------------------------------------------------
extern "C" void kernel_launch(void* const* d_in, const int* in_sizes, int n_in,
                              void* d_out, int out_size, void* d_ws, size_t ws_size,
                              hipStream_t stream) {
  const float* frames = (const float*)d_in[0];
  const int* lips_idx = (const int*)d_in[1];
  float* out = (float*)d_out;

  char* ws = (char*)d_ws;
  int* keep      = (int*)(ws);                     // 131072 B
  int* kept_t    = (int*)(ws + 131072);            // 131072 B
  int* Sp        = (int*)(ws + 262144);            // 64 B
  float* lip_sum = (float*)(ws + 262208);          // 512 B
  int* lip_cnt   = (int*)(ws + 262720);            // 512 B
  float* psum    = (float*)(ws + 263232);          // 512*80*4 = 163840 B
  int* pcnt      = (int*)(ws + 427072);            // 163840 B
  float* stage   = (float*)(ws + 590912);          // 32768*128*4 = 16 MiB

  // no zero-init needed: every word read is written first (no global atomics)

  k1_gather<<<K1_BLOCKS, 1024, 0, stream>>>(frames, lips_idx, keep, psum,
                                            pcnt, stage);
  k2_scan<<<1, 1024, 0, stream>>>(keep, kept_t, Sp, psum, pcnt, lip_sum,
                                  lip_cnt);
  k3_segments<<<NSEG, 512, 0, stream>>>(stage, kept_t, Sp, lip_sum, lip_cnt,
                                        out, out_size);
}